// Round 1
// baseline (202.082 us; speedup 1.0000x reference)
//
#include <hip/hip_runtime.h>

// ALiBi bias materialization:
//   out[h, i, j] = (j > i) ? -slopes[h] * (j - i) : 0.0f
// H=16, S=4096, output float32 [16, 4096, 4096] = 1 GiB. Pure write-BW-bound.

#define ALIBI_S 4096
#define ALIBI_H 16

__global__ __launch_bounds__(256) void alibi_bias_kernel(
    const float* __restrict__ slopes,
    float4* __restrict__ out,
    unsigned int n4)  // number of float4 elements = H*S*S/4
{
    const unsigned int stride = gridDim.x * blockDim.x;
    for (unsigned int t = blockIdx.x * blockDim.x + threadIdx.x; t < n4; t += stride) {
        const unsigned int e = t << 2;            // flat element index (max 2^28, fits u32)
        const int h = (int)(e >> 24);             // S*S = 2^24
        const int i = (int)((e >> 12) & 4095);    // S = 2^12
        const int j = (int)(e & 4095);            // first of 4 consecutive j
        const float ns = -slopes[h];              // L1-cached, 16 floats total

        float4 v;
        v.x = (j + 0 > i) ? ns * (float)(j + 0 - i) : 0.0f;
        v.y = (j + 1 > i) ? ns * (float)(j + 1 - i) : 0.0f;
        v.z = (j + 2 > i) ? ns * (float)(j + 2 - i) : 0.0f;
        v.w = (j + 3 > i) ? ns * (float)(j + 3 - i) : 0.0f;
        out[t] = v;
    }
}

extern "C" void kernel_launch(void* const* d_in, const int* in_sizes, int n_in,
                              void* d_out, int out_size, void* d_ws, size_t ws_size,
                              hipStream_t stream) {
    const float* slopes = (const float*)d_in[0];
    // d_in[1] is seq_len (=4096), compile-time constant here.
    float4* out = (float4*)d_out;

    const unsigned int n4 = (unsigned int)((unsigned long long)ALIBI_H * ALIBI_S * ALIBI_S / 4);
    const int block = 256;
    const int grid = 2048;  // 256 CUs x 8 blocks/CU; grid-stride covers the rest

    alibi_bias_kernel<<<grid, block, 0, stream>>>(slopes, out, n4);
}